// Round 6
// baseline (265.879 us; speedup 1.0000x reference)
//
#include <hip/hip_runtime.h>
#include <hip/hip_bf16.h>

// B=4, H=16, S=2048, D=64
//   S = mask ? -1e9 : QK^T/8 ; O = S@V ; out = log_softmax(O, dim=-1)
// v11: v10 profile: MfmaUtil 24.5% == the 27.5us MFMA floor; VALUBusy 40%
// is all staging (16 scalar V loads + 16 packs + 6 ds_writes / thread /
// iter). Move K->bf16 and V->V^T bf16 conversion to a BW-bound pre-kernel
// (fused with mask_pack, one launch), store PRE-SWIZZLED in global
// (chunk b4 ^= row&7; m173 pattern), and stage in attn with 4
// global_load_lds width-16 per thread per iter (linear LDS dest, XOR on
// the ds_read side — rule #21 both-sides). Numerics bit-identical to v10.
// ws needs 36MB -> gated fallback to exact v10 path if ws_size is small.

typedef __attribute__((ext_vector_type(8))) short bf16x8;
typedef __attribute__((ext_vector_type(16))) float f32x16;

#define NEGV (-1e9f)

__device__ inline unsigned cvt_bf16(float f) {
    unsigned u = __builtin_bit_cast(unsigned, f);
    u += 0x7FFFu + ((u >> 16) & 1u);   // RNE
    return u >> 16;
}
__device__ inline unsigned pk_bf16(float a, float b) {       // RNE pack (Q prologue only)
    return cvt_bf16(a) | (cvt_bf16(b) << 16);
}
__device__ inline unsigned pk_trunc(float a, float b) {      // 1 v_perm_b32
    return __builtin_amdgcn_perm(__builtin_bit_cast(unsigned, b),
                                 __builtin_bit_cast(unsigned, a), 0x07060302u);
}

#define WS_BIT_OFF  0u
#define WS_K_OFF    2097152u          // 2 MB
#define WS_V_OFF    18874368u         // 2 MB + 16.78 MB
#define WS_NEED     35651584ull       // + 16.78 MB

// ---- fused pre-kernel ----
// blocks [0,2048):    mask int32 [b][q][kk] -> bit-words bitT[b][qt][ki][q]
// blocks [2048,6144): K f32 -> bf16, swizzled chunks Kswz[bh][ki][row][b4]
//                     chunk(b4) holds K[row][(b4^(row&7))*8 .. +7]
// blocks [6144,10240): V f32 -> V^T bf16, swizzled Vtswz[bh][ki][d][b4]
//                     chunk(b4) holds V[k0+(b4^(d&7))*8+j][d], j=0..7
__global__ __launch_bounds__(256)
void preconv(const int* __restrict__ M, const float* __restrict__ K,
             const float* __restrict__ V, unsigned long long* __restrict__ bitT,
             unsigned short* __restrict__ Kswz, unsigned short* __restrict__ Vtswz) {
    const int tid  = threadIdx.x;
    const int lane = tid & 63;
    const int wave = tid >> 6;
    const int bid  = blockIdx.x;

    if (bid < 2048) {                       // ---- mask pack ----
        const int gw = (bid * 256 + tid) >> 6;      // row id 0..8191
        const int b  = gw >> 11;
        const int qt = (gw >> 8) & 7;
        const int q  = gw & 255;
        const size_t mbase = (size_t)gw * 2048;
        unsigned long long* dst = bitT + (size_t)(b * 8 + qt) * 32 * 256 + q;
#pragma unroll 4
        for (int ki = 0; ki < 32; ki++) {
            const int m = M[mbase + ki * 64 + lane];
            const unsigned long long bal = __ballot(m != 0);
            if (lane == 0) dst[ki * 256] = bal;
        }
    } else if (bid < 6144) {                // ---- K convert (1 chunk / thread) ----
        const unsigned g   = (unsigned)(bid - 2048) * 256 + tid;   // 0..1048575
        const int b4  = g & 7;
        const int row = (g >> 3) & 63;
        const int d0  = (b4 ^ (row & 7)) * 8;
        const float* src = K + (size_t)(g >> 3) * 64 + d0;         // (bh*2048+ki*64+row)*64 + d0
        const float4 f0 = *(const float4*)(src);
        const float4 f1 = *(const float4*)(src + 4);
        uint4 p;
        p.x = pk_trunc(f0.x, f0.y); p.y = pk_trunc(f0.z, f0.w);
        p.z = pk_trunc(f1.x, f1.y); p.w = pk_trunc(f1.z, f1.w);
        *(uint4*)&Kswz[(size_t)g * 8] = p;
    } else {                                // ---- V^T convert (1 (bh,ki,kgrp) / wave) ----
        const int j    = (bid - 6144) * 4 + wave;   // 0..16383
        const int kgrp = j & 7;
        const int ki   = (j >> 3) & 31;
        const int bh   = j >> 8;
        const size_t vbase = ((size_t)(bh * 2048 + ki * 64 + kgrp * 8)) * 64 + lane;
        float v[8];
#pragma unroll
        for (int jj = 0; jj < 8; jj++) v[jj] = V[vbase + jj * 64];
        uint4 p;
        p.x = pk_trunc(v[0], v[1]); p.y = pk_trunc(v[2], v[3]);
        p.z = pk_trunc(v[4], v[5]); p.w = pk_trunc(v[6], v[7]);
        const size_t chunk = ((size_t)(bh * 32 + ki) * 64 + lane) * 8 + (kgrp ^ (lane & 7));
        *(uint4*)&Vtswz[chunk * 8] = p;
    }
}

// ---- fast attention: global_load_lds staging of pre-converted tiles ----
__global__ __launch_bounds__(256, 4)
void attn_fast(const float* __restrict__ Q,
               const unsigned short* __restrict__ Kswz,
               const unsigned short* __restrict__ Vtswz,
               const unsigned long long* __restrict__ bitT,
               float* __restrict__ Out) {
    __shared__ __attribute__((aligned(16))) unsigned short sK[2][64 * 64];   // 8 KB x2
    __shared__ __attribute__((aligned(16))) unsigned short sVt[2][64 * 64];  // 8 KB x2
    // total 32 KB -> 4 blocks/CU

    const int tid  = threadIdx.x;
    const int wave = tid >> 6;
    const int lane = tid & 63;
    const int half = lane >> 5;
    const int l32  = lane & 31;

    const int bid = blockIdx.x;
    const int h   = bid & 15;
    const int qt2 = (bid >> 4) & 15;
    const int b   = bid >> 8;
    const int bh  = b * 16 + h;
    const int q0  = qt2 * 128;
    const int qt  = qt2 >> 1;
    const int qh  = qt2 & 1;

    const float* Qb = Q + (size_t)(bh * 2048 + q0) * 64;
    const unsigned short* Kt = Kswz  + ((size_t)bh << 17);   // bh*2048*64
    const unsigned short* Vt = Vtswz + ((size_t)bh << 17);
    const unsigned long long* Bt = bitT + (size_t)(b * 8 + qt) * 32 * 256
                                 + qh * 128 + wave * 32 + l32;

    // ---- stage tile ki into buffer buf: 4 x global_load_lds (16B/lane) ----
    #define STAGE(buf, ki) do {                                                   \
        const unsigned short* kg_ = Kt + ((ki) << 12) + wave * 1024 + lane * 8;   \
        const unsigned short* vg_ = Vt + ((ki) << 12) + wave * 1024 + lane * 8;   \
        unsigned short* ks_ = &sK[buf][wave * 1024];                              \
        unsigned short* vs_ = &sVt[buf][wave * 1024];                             \
        __builtin_amdgcn_global_load_lds(                                         \
            (const __attribute__((address_space(1))) void*)kg_,                   \
            (__attribute__((address_space(3))) void*)ks_, 16, 0, 0);              \
        __builtin_amdgcn_global_load_lds(                                         \
            (const __attribute__((address_space(1))) void*)(kg_ + 512),           \
            (__attribute__((address_space(3))) void*)(ks_ + 512), 16, 0, 0);      \
        __builtin_amdgcn_global_load_lds(                                         \
            (const __attribute__((address_space(1))) void*)vg_,                   \
            (__attribute__((address_space(3))) void*)vs_, 16, 0, 0);              \
        __builtin_amdgcn_global_load_lds(                                         \
            (const __attribute__((address_space(1))) void*)(vg_ + 512),           \
            (__attribute__((address_space(3))) void*)(vs_ + 512), 16, 0, 0);      \
    } while (0)

    STAGE(0, 0);
    unsigned long long mw = Bt[0];

    // ---- Q fragments (pre-scaled by 1/8), RNE, live all kernel ----
    bf16x8 qF[4];
    {
        const float* qr = Qb + (size_t)(wave * 32 + l32) * 64 + half * 8;
#pragma unroll
        for (int dk = 0; dk < 4; dk++) {
            const float4 f0 = *(const float4*)(qr + dk * 16);
            const float4 f1 = *(const float4*)(qr + dk * 16 + 4);
            union { bf16x8 v; unsigned u[4]; } t;
            t.u[0] = pk_bf16(f0.x * 0.125f, f0.y * 0.125f);
            t.u[1] = pk_bf16(f0.z * 0.125f, f0.w * 0.125f);
            t.u[2] = pk_bf16(f1.x * 0.125f, f1.y * 0.125f);
            t.u[3] = pk_bf16(f1.z * 0.125f, f1.w * 0.125f);
            qF[dk] = t.v;
        }
    }

    f32x16 Oacc[2];
#pragma unroll
    for (int db = 0; db < 2; db++)
#pragma unroll
        for (int r = 0; r < 16; r++) Oacc[db][r] = 0.f;

    __syncthreads();   // drains tile-0 stage (vmcnt0) + all waves arrived

    const int swz = (l32 & 7) << 4;   // byte XOR, both-sides with preconv's layout

    for (int ki = 0; ki < 32; ki++) {
        const int cur = ki & 1;

        // issue next tile's stage + mask prefetch; lands before end-of-iter barrier
        unsigned long long mwN = 0;
        if (ki < 31) {
            STAGE(cur ^ 1, ki + 1);
            mwN = Bt[(ki + 1) * 256];
        }

        const char* sKc = (const char*)sK[cur];
        const char* sVc = (const char*)sVt[cur];

#pragma unroll
        for (int jk = 0; jk < 2; jk++) {
            bf16x8 aK[4];
#pragma unroll
            for (int dk = 0; dk < 4; dk++)
                aK[dk] = *(const bf16x8*)(sKc +
                    ((((jk * 32 + l32) * 128) + dk * 32 + half * 16) ^ swz));
            bf16x8 bV[2][2];
#pragma unroll
            for (int p = 0; p < 2; p++)
#pragma unroll
                for (int db = 0; db < 2; db++)
                    bV[p][db] = *(const bf16x8*)(sVc +
                        ((((db * 32 + l32) * 128) + (jk * 2 + p) * 32 + half * 16) ^ swz));

            // bit for acc[rg*4+w] = jk*32 + rg*8 + half*4 + w  (q = l32's row word)
            const unsigned b32 = (unsigned)(mw >> (jk * 32));
            const unsigned bsh = b32 >> (half * 4);

            // masked init: -1e9 + qk trunc-packs to EXACTLY bf16(-1e9)
            f32x16 acc;
#pragma unroll
            for (int rg = 0; rg < 4; rg++) {
                const unsigned nib = bsh >> (rg * 8);
                acc[rg * 4 + 0] = (nib & 1u) ? NEGV : 0.f;
                acc[rg * 4 + 1] = (nib & 2u) ? NEGV : 0.f;
                acc[rg * 4 + 2] = (nib & 4u) ? NEGV : 0.f;
                acc[rg * 4 + 3] = (nib & 8u) ? NEGV : 0.f;
            }
#pragma unroll
            for (int dk = 0; dk < 4; dk++)
                acc = __builtin_amdgcn_mfma_f32_32x32x16_bf16(aK[dk], qF[dk], acc, 0, 0, 0);

            // in-register S^T -> S transpose via permlane32_swap (HK T12)
#pragma unroll
            for (int p = 0; p < 2; p++) {
                const unsigned P0 = pk_trunc(acc[p * 8 + 0], acc[p * 8 + 1]);
                const unsigned P1 = pk_trunc(acc[p * 8 + 2], acc[p * 8 + 3]);
                const unsigned P2 = pk_trunc(acc[p * 8 + 4], acc[p * 8 + 5]);
                const unsigned P3 = pk_trunc(acc[p * 8 + 6], acc[p * 8 + 7]);
                auto r02 = __builtin_amdgcn_permlane32_swap(P0, P2, false, false);
                auto r13 = __builtin_amdgcn_permlane32_swap(P1, P3, false, false);
                union { bf16x8 v; unsigned u[4]; } aS;
                aS.u[0] = (unsigned)r02[0];
                aS.u[1] = (unsigned)r13[0];
                aS.u[2] = (unsigned)r02[1];
                aS.u[3] = (unsigned)r13[1];
#pragma unroll
                for (int db = 0; db < 2; db++)
                    Oacc[db] = __builtin_amdgcn_mfma_f32_32x32x16_bf16(aS.v, bV[p][db], Oacc[db], 0, 0, 0);
            }
        }

        mw = mwN;
        __syncthreads();   // drains next-tile stage; protects buf reuse
    }

    // ---- epilogue: log_softmax over d=64 ----
    float* Ob = Out + (size_t)bh * 2048 * 64;
#pragma unroll
    for (int r = 0; r < 16; r++) {
        const float v0 = Oacc[0][r], v1 = Oacc[1][r];
        float mx = fmaxf(v0, v1);
#pragma unroll
        for (int off = 1; off < 32; off <<= 1)
            mx = fmaxf(mx, __shfl_xor(mx, off, 64));
        float s = __expf(v0 - mx) + __expf(v1 - mx);
#pragma unroll
        for (int off = 1; off < 32; off <<= 1)
            s += __shfl_xor(s, off, 64);
        const float lse = mx + __logf(s);
        const int qrow = q0 + wave * 32 + (r & 3) + 8 * (r >> 2) + 4 * half;
        Ob[(size_t)qrow * 64 + l32]      = v0 - lse;
        Ob[(size_t)qrow * 64 + 32 + l32] = v1 - lse;
    }
    #undef STAGE
}

// ================= fallback path (exact v10) =================
__global__ __launch_bounds__(256)
void mask_pack(const int* __restrict__ M, unsigned long long* __restrict__ bitT) {
    const int lane = threadIdx.x & 63;
    const int gw   = (blockIdx.x * 256 + threadIdx.x) >> 6;
    const int b    = gw >> 11;
    const int qt   = (gw >> 8) & 7;
    const int q    = gw & 255;
    const size_t mbase = (size_t)gw * 2048;
    unsigned long long* dst = bitT + (size_t)(b * 8 + qt) * 32 * 256 + q;
#pragma unroll 4
    for (int ki = 0; ki < 32; ki++) {
        const int m = M[mbase + ki * 64 + lane];
        const unsigned long long bal = __ballot(m != 0);
        if (lane == 0) dst[ki * 256] = bal;
    }
}

__global__ __launch_bounds__(256, 4)
void attn_v10(const float* __restrict__ Q, const float* __restrict__ K,
              const float* __restrict__ V,
              const unsigned long long* __restrict__ bitT,
              float* __restrict__ Out) {
    __shared__ __attribute__((aligned(16))) unsigned short sK[2][64 * 72];
    __shared__ __attribute__((aligned(16))) unsigned short sVt[2][64 * 72];

    const int tid  = threadIdx.x;
    const int wave = tid >> 6;
    const int lane = tid & 63;
    const int half = lane >> 5;
    const int l32  = lane & 31;

    const int bid = blockIdx.x;
    const int h   = bid & 15;
    const int qt2 = (bid >> 4) & 15;
    const int b   = bid >> 8;
    const int bh  = b * 16 + h;
    const int q0  = qt2 * 128;
    const int qt  = qt2 >> 1;
    const int qh  = qt2 & 1;

    const float* Qb = Q + (size_t)(bh * 2048 + q0) * 64;
    const float* Kb = K + (size_t)bh * 2048 * 64;
    const float* Vb = V + (size_t)bh * 2048 * 64;
    const unsigned long long* Bt = bitT + (size_t)(b * 8 + qt) * 32 * 256
                                 + qh * 128 + wave * 32 + l32;

    float4 kp[4];
    float  vp[16];
    unsigned long long mw = Bt[0];
    const int krow = tid >> 4, kc4 = tid & 15;
#pragma unroll
    for (int i = 0; i < 4; i++)
        kp[i] = *(const float4*)(Kb + (size_t)(krow + i * 16) * 64 + kc4 * 4);
#pragma unroll
    for (int i = 0; i < 2; i++) {
        const int kb = (wave * 2 + i) * 8;
#pragma unroll
        for (int j = 0; j < 8; j++)
            vp[i * 8 + j] = Vb[(size_t)(kb + j) * 64 + lane];
    }

    bf16x8 qF[4];
    {
        const float* qr = Qb + (size_t)(wave * 32 + l32) * 64 + half * 8;
#pragma unroll
        for (int dk = 0; dk < 4; dk++) {
            const float4 f0 = *(const float4*)(qr + dk * 16);
            const float4 f1 = *(const float4*)(qr + dk * 16 + 4);
            union { bf16x8 v; unsigned u[4]; } t;
            t.u[0] = pk_bf16(f0.x * 0.125f, f0.y * 0.125f);
            t.u[1] = pk_bf16(f0.z * 0.125f, f0.w * 0.125f);
            t.u[2] = pk_bf16(f1.x * 0.125f, f1.y * 0.125f);
            t.u[3] = pk_bf16(f1.z * 0.125f, f1.w * 0.125f);
            qF[dk] = t.v;
        }
    }

    f32x16 Oacc[2];
#pragma unroll
    for (int db = 0; db < 2; db++)
#pragma unroll
        for (int r = 0; r < 16; r++) Oacc[db][r] = 0.f;

    for (int ki = 0; ki < 32; ki++) {
        const int cur = ki & 1;
#pragma unroll
        for (int i = 0; i < 4; i++) {
            uint2 p;
            p.x = pk_trunc(kp[i].x, kp[i].y);
            p.y = pk_trunc(kp[i].z, kp[i].w);
            *(uint2*)&sK[cur][(krow + i * 16) * 72 + kc4 * 4] = p;
        }
#pragma unroll
        for (int i = 0; i < 2; i++) {
            const int kb = (wave * 2 + i) * 8;
            uint4 p4;
            p4.x = pk_trunc(vp[i * 8 + 0], vp[i * 8 + 1]);
            p4.y = pk_trunc(vp[i * 8 + 2], vp[i * 8 + 3]);
            p4.z = pk_trunc(vp[i * 8 + 4], vp[i * 8 + 5]);
            p4.w = pk_trunc(vp[i * 8 + 6], vp[i * 8 + 7]);
            *(uint4*)&sVt[cur][lane * 72 + kb] = p4;
        }

        __syncthreads();

        unsigned long long mwN = 0;
        if (ki < 31) {
            const int kn = (ki + 1) * 64;
            mwN = Bt[(ki + 1) * 256];
#pragma unroll
            for (int i = 0; i < 4; i++)
                kp[i] = *(const float4*)(Kb + (size_t)(kn + krow + i * 16) * 64 + kc4 * 4);
#pragma unroll
            for (int i = 0; i < 2; i++) {
                const int kb = (wave * 2 + i) * 8;
#pragma unroll
                for (int j = 0; j < 8; j++)
                    vp[i * 8 + j] = Vb[(size_t)(kn + kb + j) * 64 + lane];
            }
        }

#pragma unroll
        for (int jk = 0; jk < 2; jk++) {
            bf16x8 aK[4];
#pragma unroll
            for (int dk = 0; dk < 4; dk++)
                aK[dk] = *(const bf16x8*)&sK[cur][(jk * 32 + l32) * 72 + dk * 16 + half * 8];
            bf16x8 bV[2][2];
#pragma unroll
            for (int p = 0; p < 2; p++)
#pragma unroll
                for (int db = 0; db < 2; db++)
                    bV[p][db] = *(const bf16x8*)&sVt[cur][(db * 32 + l32) * 72 + (jk * 2 + p) * 16 + half * 8];

            const unsigned b32 = (unsigned)(mw >> (jk * 32));
            const unsigned bsh = b32 >> (half * 4);

            f32x16 acc;
#pragma unroll
            for (int rg = 0; rg < 4; rg++) {
                const unsigned nib = bsh >> (rg * 8);
                acc[rg * 4 + 0] = (nib & 1u) ? NEGV : 0.f;
                acc[rg * 4 + 1] = (nib & 2u) ? NEGV : 0.f;
                acc[rg * 4 + 2] = (nib & 4u) ? NEGV : 0.f;
                acc[rg * 4 + 3] = (nib & 8u) ? NEGV : 0.f;
            }
#pragma unroll
            for (int dk = 0; dk < 4; dk++)
                acc = __builtin_amdgcn_mfma_f32_32x32x16_bf16(aK[dk], qF[dk], acc, 0, 0, 0);

#pragma unroll
            for (int p = 0; p < 2; p++) {
                const unsigned P0 = pk_trunc(acc[p * 8 + 0], acc[p * 8 + 1]);
                const unsigned P1 = pk_trunc(acc[p * 8 + 2], acc[p * 8 + 3]);
                const unsigned P2 = pk_trunc(acc[p * 8 + 4], acc[p * 8 + 5]);
                const unsigned P3 = pk_trunc(acc[p * 8 + 6], acc[p * 8 + 7]);
                auto r02 = __builtin_amdgcn_permlane32_swap(P0, P2, false, false);
                auto r13 = __builtin_amdgcn_permlane32_swap(P1, P3, false, false);
                union { bf16x8 v; unsigned u[4]; } aS;
                aS.u[0] = (unsigned)r02[0];
                aS.u[1] = (unsigned)r13[0];
                aS.u[2] = (unsigned)r02[1];
                aS.u[3] = (unsigned)r13[1];
#pragma unroll
                for (int db = 0; db < 2; db++)
                    Oacc[db] = __builtin_amdgcn_mfma_f32_32x32x16_bf16(aS.v, bV[p][db], Oacc[db], 0, 0, 0);
            }
        }

        mw = mwN;
    }

    float* Ob = Out + (size_t)bh * 2048 * 64;
#pragma unroll
    for (int r = 0; r < 16; r++) {
        const float v0 = Oacc[0][r], v1 = Oacc[1][r];
        float mx = fmaxf(v0, v1);
#pragma unroll
        for (int off = 1; off < 32; off <<= 1)
            mx = fmaxf(mx, __shfl_xor(mx, off, 64));
        float s = __expf(v0 - mx) + __expf(v1 - mx);
#pragma unroll
        for (int off = 1; off < 32; off <<= 1)
            s += __shfl_xor(s, off, 64);
        const float lse = mx + __logf(s);
        const int qrow = q0 + wave * 32 + (r & 3) + 8 * (r >> 2) + 4 * half;
        Ob[(size_t)qrow * 64 + l32]      = v0 - lse;
        Ob[(size_t)qrow * 64 + 32 + l32] = v1 - lse;
    }
}

extern "C" void kernel_launch(void* const* d_in, const int* in_sizes, int n_in,
                              void* d_out, int out_size, void* d_ws, size_t ws_size,
                              hipStream_t stream) {
    const float* Q = (const float*)d_in[0];
    const float* K = (const float*)d_in[1];
    const float* V = (const float*)d_in[2];
    const int*   M = (const int*)d_in[3];
    float* Out = (float*)d_out;
    unsigned long long* bitT = (unsigned long long*)d_ws;

    if (ws_size >= WS_NEED) {
        unsigned short* Kswz  = (unsigned short*)((char*)d_ws + WS_K_OFF);
        unsigned short* Vtswz = (unsigned short*)((char*)d_ws + WS_V_OFF);
        preconv<<<dim3(10240), dim3(256), 0, stream>>>(M, K, V, bitT, Kswz, Vtswz);
        attn_fast<<<dim3(1024), dim3(256), 0, stream>>>(Q, Kswz, Vtswz, bitT, Out);
    } else {
        mask_pack<<<dim3(2048), dim3(256), 0, stream>>>(M, bitT);
        attn_v10<<<dim3(1024), dim3(256), 0, stream>>>(Q, K, V, bitT, Out);
    }
}